// Round 7
// baseline (4629.147 us; speedup 1.0000x reference)
//
#include <hip/hip_runtime.h>
#include <math.h>

// Fixed instance constants.
#define Nn 4096          // n = m * tmax
#define BSc 32           // batch size (border rows)
#define NB 128           // block size
#define NBB 32           // sub-block for recursive factorization
#define NBLK 33          // block-rows: 32 full + 1 border (32 rows)
#define NK 32            // factorization steps
#define TILE_ELEMS (NB * NB)
#define NTILES 561       // NBLK*(NBLK+1)/2 lower tiles

typedef float f32x4 __attribute__((ext_vector_type(4)));
typedef short bf16x8 __attribute__((ext_vector_type(8)));

// Packed lower-block-triangular storage: tile(i,j), 0<=j<=i<=32, stored
// column-major by block-column. 561 tiles * 64KB = 36.8 MB.
__device__ __forceinline__ size_t tile_off(int i, int j) {
  return ((size_t)(j * NBLK - (j * (j - 1)) / 2 + (i - j))) * TILE_ELEMS;
}

// fp32 -> bf16 (round-to-nearest-even), raw bits; values are finite here.
__device__ __forceinline__ unsigned short f2bf(float f) {
  union { float f; unsigned int u; } v; v.f = f;
  unsigned int r = v.u + 0x7fffu + ((v.u >> 16) & 1u);
  return (unsigned short)(r >> 16);
}
__device__ __forceinline__ float bf2f(unsigned short b) {
  union { unsigned int u; float f; } v; v.u = ((unsigned int)b) << 16;
  return v.f;
}

// ---------------------------------------------------------------------------
// prep: fill stored tiles from the virtual bordered matrix.
// ---------------------------------------------------------------------------
__global__ __launch_bounds__(256) void prep(const float* __restrict__ Y,
                                            const float* __restrict__ mu,
                                            const float* __restrict__ Kp,
                                            const float* __restrict__ Sg,
                                            float* __restrict__ W) {
  int bid = blockIdx.x;
  int j = 0;
  while (j + 1 < NBLK) {
    int nxt = (j + 1) * NBLK - ((j + 1) * j) / 2;
    if (bid < nxt) break;
    ++j;
  }
  int start = j * NBLK - (j * (j - 1)) / 2;
  int i = j + (bid - start);
  float* T = W + tile_off(i, j);
  int tid = threadIdx.x;
  for (int idx = tid; idx < TILE_ELEMS; idx += 256) {
    int li = idx >> 7, lj = idx & 127;
    int gr = i * NB + li, gc = j * NB + lj;
    float v = 0.0f;
    if (gr < Nn) {
      v = Kp[(size_t)gr * Nn + gc];
      if (gr == gc) v += Sg[(size_t)gr * Nn + gr];
    } else {
      int b = gr - Nn;
      if (b < BSc && gc < Nn) v = mu[gc] - Y[(size_t)b * Nn + gc];
    }
    T[idx] = v;
  }
}

// ---------------------------------------------------------------------------
// panel: fused potf2 + trsm for step k. Each WG (i = k+1+blockIdx.x):
//   1) loads tile(k,k) into LDS and factors it REDUNDANTLY (parallel across
//      WGs). A-phase = round-3/4-proven Crout register factorization
//      (rank-1 variant from r5/r6 is quarantined pending the hang bisect).
//   2) solves its own 128-row tile X against L_kk (blocked fwd substitution)
//   3) epilogue: split-bf16 (hi/lo) panel store for the MFMA syrk.
//   WG 0 also stores diag(L_kk) to Ld for the logdet.
// ---------------------------------------------------------------------------
__global__ __launch_bounds__(256) void panel(float* __restrict__ W,
                                             unsigned short* __restrict__ PH,
                                             unsigned short* __restrict__ PL,
                                             float* __restrict__ Ld,
                                             int k) {
  __shared__ float Td[NB][NB + 1];
  __shared__ float X[NB][NB + 1];
  __shared__ float dinv_sh[NB];
  int tid = threadIdx.x;
  int i = k + 1 + blockIdx.x;
  int rows = (i == NBLK - 1) ? BSc : NB;
  const float* Gd = W + tile_off(k, k);
  const float* Gx = W + tile_off(i, k);
  for (int idx = tid; idx < TILE_ELEMS / 4; idx += 256) {
    float4 v = ((const float4*)Gd)[idx];
    float4 u = ((const float4*)Gx)[idx];
    int r = idx >> 5, c = (idx & 31) * 4;
    Td[r][c] = v.x; Td[r][c + 1] = v.y; Td[r][c + 2] = v.z; Td[r][c + 3] = v.w;
    if (r < rows) { X[r][c] = u.x; X[r][c + 1] = u.y; X[r][c + 2] = u.z; X[r][c + 3] = u.w; }
    else          { X[r][c] = 0.0f; X[r][c + 1] = 0.0f; X[r][c + 2] = 0.0f; X[r][c + 3] = 0.0f; }
  }
  __syncthreads();
  int lane = tid & 63, wid = tid >> 6;

  // ---- in-LDS factorization of Td (recursive 32-blocking) ----
#pragma unroll 1
  for (int kb = 0; kb < 4; ++kb) {
    int o = kb * NBB;
    // A: 32x32 diagonal block, Crout register factorization in wave 0
    // (verbatim from the r3/r4-proven potf2).
    if (wid == 0) {
      int ii = lane & 31;
      float cc[NBB];
#pragma unroll
      for (int p = 0; p < NBB; ++p) cc[p] = Td[o + ii][o + p];
#pragma unroll
      for (int j = 0; j < NBB; ++j) {
        float s = cc[j];
#pragma unroll
        for (int p = 0; p < NBB; ++p) {
          if (p < j) s -= cc[p] * __shfl(cc[p], j, 64);
        }
        float sj = __shfl(s, j, 64);
        float d = sqrtf(sj);
        if (ii == j) cc[j] = d;
        else if (ii > j) cc[j] = s / d;
      }
      if (lane < 32) {
#pragma unroll
        for (int p = 0; p < NBB; ++p) {
          if (p <= ii) Td[o + ii][o + p] = cc[p];
        }
      }
    }
    __syncthreads();
    if (tid < NBB) dinv_sh[o + tid] = 1.0f / Td[o + tid][o + tid];
    __syncthreads();
    int R = NB - o - NBB;   // trailing rows inside Td: 96, 64, 32, 0
    if (R > 0) {
      // B: solve Td trailing rows against the factored 32x32 triangle.
      if (tid < R) {
        int r = o + NBB + tid;
        float x[NBB];
#pragma unroll
        for (int p = 0; p < NBB; ++p) x[p] = Td[r][o + p];
#pragma unroll
        for (int j = 0; j < NBB; ++j) {
          float s = x[j];
#pragma unroll
          for (int p = 0; p < NBB; ++p) {
            if (p < j) s -= x[p] * Td[o + j][o + p];
          }
          x[j] = s * dinv_sh[o + j];
        }
#pragma unroll
        for (int p = 0; p < NBB; ++p) Td[r][o + p] = x[p];
      }
      __syncthreads();
      // C: trailing rank-32 update, lower 4x4 tiles only.
      int TL = R >> 2;
      int ntile = TL * (TL + 1) / 2;
#pragma unroll 1
      for (int t = tid; t < ntile; t += 256) {
        int ti = (int)((sqrtf(8.0f * t + 1.0f) - 1.0f) * 0.5f);
        while ((ti + 1) * (ti + 2) / 2 <= t) ++ti;
        while (ti * (ti + 1) / 2 > t) --ti;
        int tj = t - ti * (ti + 1) / 2;
        int tr = o + NBB + ti * 4, tc = o + NBB + tj * 4;
        float acc[4][4];
#pragma unroll
        for (int m = 0; m < 4; ++m)
#pragma unroll
          for (int n = 0; n < 4; ++n) acc[m][n] = 0.0f;
#pragma unroll 1
        for (int p = 0; p < NBB; ++p) {
          float a0 = Td[tr][o + p], a1 = Td[tr + 1][o + p],
                a2 = Td[tr + 2][o + p], a3 = Td[tr + 3][o + p];
          float b0 = Td[tc][o + p], b1 = Td[tc + 1][o + p],
                b2 = Td[tc + 2][o + p], b3 = Td[tc + 3][o + p];
          acc[0][0] += a0 * b0; acc[0][1] += a0 * b1; acc[0][2] += a0 * b2; acc[0][3] += a0 * b3;
          acc[1][0] += a1 * b0; acc[1][1] += a1 * b1; acc[1][2] += a1 * b2; acc[1][3] += a1 * b3;
          acc[2][0] += a2 * b0; acc[2][1] += a2 * b1; acc[2][2] += a2 * b2; acc[2][3] += a2 * b3;
          acc[3][0] += a3 * b0; acc[3][1] += a3 * b1; acc[3][2] += a3 * b2; acc[3][3] += a3 * b3;
        }
#pragma unroll
        for (int m = 0; m < 4; ++m)
#pragma unroll
          for (int n = 0; n < 4; ++n) Td[tr + m][tc + n] -= acc[m][n];
      }
    }
    __syncthreads();
  }

  // WG 0 records diag(L_kk) for the logdet.
  if (blockIdx.x == 0 && tid < NB) Ld[k * NB + tid] = Td[tid][tid];

  // ---- blocked forward substitution of X against factored Td ----
  int rtile = (tid >> 3) * 4;
  int ctile = (tid & 7) * 4;
#pragma unroll 1
  for (int jb = 0; jb < 4; ++jb) {
    int o = jb * NBB;
    if (jb > 0) {
      float acc[4][4];
#pragma unroll
      for (int m = 0; m < 4; ++m)
#pragma unroll
        for (int n = 0; n < 4; ++n) acc[m][n] = 0.0f;
#pragma unroll 1
      for (int p = 0; p < o; ++p) {
        float a0 = X[rtile][p], a1 = X[rtile + 1][p],
              a2 = X[rtile + 2][p], a3 = X[rtile + 3][p];
        float b0 = Td[o + ctile][p], b1 = Td[o + ctile + 1][p],
              b2 = Td[o + ctile + 2][p], b3 = Td[o + ctile + 3][p];
        acc[0][0] += a0 * b0; acc[0][1] += a0 * b1; acc[0][2] += a0 * b2; acc[0][3] += a0 * b3;
        acc[1][0] += a1 * b0; acc[1][1] += a1 * b1; acc[1][2] += a1 * b2; acc[1][3] += a1 * b3;
        acc[2][0] += a2 * b0; acc[2][1] += a2 * b1; acc[2][2] += a2 * b2; acc[2][3] += a2 * b3;
        acc[3][0] += a3 * b0; acc[3][1] += a3 * b1; acc[3][2] += a3 * b2; acc[3][3] += a3 * b3;
      }
#pragma unroll
      for (int m = 0; m < 4; ++m)
#pragma unroll
        for (int n = 0; n < 4; ++n) X[rtile + m][o + ctile + n] -= acc[m][n];
      __syncthreads();
    }
    if (tid < NB) {
      int r = tid;
      float x[NBB];
#pragma unroll
      for (int p = 0; p < NBB; ++p) x[p] = X[r][o + p];
#pragma unroll
      for (int j = 0; j < NBB; ++j) {
        float s = x[j];
#pragma unroll
        for (int p = 0; p < NBB; ++p) {
          if (p < j) s -= x[p] * Td[o + j][o + p];
        }
        x[j] = s * dinv_sh[o + j];
      }
#pragma unroll
      for (int p = 0; p < NBB; ++p) X[r][o + p] = x[p];
    }
    __syncthreads();
  }

  // Epilogue: split-bf16 panel store (all 128 rows; dead border rows are 0).
  int r = tid >> 1, hf = tid & 1;
  unsigned short* ph = PH + (size_t)i * TILE_ELEMS + (size_t)r * NB + hf * 64;
  unsigned short* pl = PL + (size_t)i * TILE_ELEMS + (size_t)r * NB + hf * 64;
#pragma unroll 1
  for (int ch = 0; ch < 8; ++ch) {
    unsigned short hb[8], lb[8];
#pragma unroll
    for (int e = 0; e < 8; ++e) {
      float v = X[r][hf * 64 + ch * 8 + e];
      unsigned short h = f2bf(v);
      hb[e] = h;
      lb[e] = f2bf(v - bf2f(h));
    }
    *reinterpret_cast<uint4*>(&ph[ch * 8]) = *reinterpret_cast<const uint4*>(hb);
    *reinterpret_cast<uint4*>(&pl[ch * 8]) = *reinterpret_cast<const uint4*>(lb);
  }
}

// ---------------------------------------------------------------------------
// syrk: tile(i,j) -= P_i * P_j^T via split-bf16 MFMA (hi*hi + lo*hi + hi*lo),
// fp32 accumulate. 128x128 tile, 4 waves (2x2), 4x4 16x16 fragments per wave,
// K = 128 in 4 steps of 32. Panels pre-converted & zero-padded -> guard-free.
// ---------------------------------------------------------------------------
__global__ __launch_bounds__(256) void syrk(const unsigned short* __restrict__ PH,
                                            const unsigned short* __restrict__ PL,
                                            float* __restrict__ W, int k) {
  int i = k + 1 + blockIdx.x, j = k + 1 + blockIdx.y;
  if (i < j) return;
  const unsigned short* Ahg = PH + (size_t)i * TILE_ELEMS;
  const unsigned short* Alg = PL + (size_t)i * TILE_ELEMS;
  const unsigned short* Bhg = PH + (size_t)j * TILE_ELEMS;
  const unsigned short* Blg = PL + (size_t)j * TILE_ELEMS;
  float* C = W + tile_off(i, j);
  __shared__ unsigned short Ah[NB][40], Al[NB][40], Bh[NB][40], Bl[NB][40];
  int tid = threadIdx.x, lane = tid & 63, wid = tid >> 6;
  int wr = wid >> 1, wc = wid & 1, lm = lane & 15, lk = lane >> 4;
  f32x4 acc[4][4];
#pragma unroll
  for (int m = 0; m < 4; ++m)
#pragma unroll
    for (int n = 0; n < 4; ++n) acc[m][n] = (f32x4)0.0f;
  int r = tid >> 1, hf = tid & 1;
#pragma unroll 1
  for (int kb = 0; kb < 4; ++kb) {
    int kbase = kb * 32;
    if (kb) __syncthreads();
#pragma unroll
    for (int c = 0; c < 2; ++c) {
      int lc = (hf * 2 + c) * 8;          // LDS k-offset (bf16 elems)
      int kc = kbase + lc;                // global k-offset
      *reinterpret_cast<uint4*>(&Ah[r][lc]) = *reinterpret_cast<const uint4*>(&Ahg[(size_t)r * NB + kc]);
      *reinterpret_cast<uint4*>(&Al[r][lc]) = *reinterpret_cast<const uint4*>(&Alg[(size_t)r * NB + kc]);
      *reinterpret_cast<uint4*>(&Bh[r][lc]) = *reinterpret_cast<const uint4*>(&Bhg[(size_t)r * NB + kc]);
      *reinterpret_cast<uint4*>(&Bl[r][lc]) = *reinterpret_cast<const uint4*>(&Blg[(size_t)r * NB + kc]);
    }
    __syncthreads();
    bf16x8 ah[4], al[4], bh[4], bl[4];
#pragma unroll
    for (int mt = 0; mt < 4; ++mt) {
      int row = wr * 64 + mt * 16 + lm;
      ah[mt] = *reinterpret_cast<const bf16x8*>(&Ah[row][lk * 8]);
      al[mt] = *reinterpret_cast<const bf16x8*>(&Al[row][lk * 8]);
    }
#pragma unroll
    for (int nt = 0; nt < 4; ++nt) {
      int col = wc * 64 + nt * 16 + lm;
      bh[nt] = *reinterpret_cast<const bf16x8*>(&Bh[col][lk * 8]);
      bl[nt] = *reinterpret_cast<const bf16x8*>(&Bl[col][lk * 8]);
    }
#pragma unroll
    for (int mt = 0; mt < 4; ++mt)
#pragma unroll
      for (int nt = 0; nt < 4; ++nt) {
        acc[mt][nt] = __builtin_amdgcn_mfma_f32_16x16x32_bf16(ah[mt], bh[nt], acc[mt][nt], 0, 0, 0);
        acc[mt][nt] = __builtin_amdgcn_mfma_f32_16x16x32_bf16(al[mt], bh[nt], acc[mt][nt], 0, 0, 0);
        acc[mt][nt] = __builtin_amdgcn_mfma_f32_16x16x32_bf16(ah[mt], bl[nt], acc[mt][nt], 0, 0, 0);
      }
  }
#pragma unroll
  for (int mt = 0; mt < 4; ++mt)
#pragma unroll
    for (int nt = 0; nt < 4; ++nt) {
#pragma unroll
      for (int q = 0; q < 4; ++q) {
        int rr = wr * 64 + mt * 16 + lk * 4 + q;
        int cc = wc * 64 + nt * 16 + lm;
        C[rr * NB + cc] -= acc[mt][nt][q];
      }
    }
}

// ---------------------------------------------------------------------------
// finalize: -lml from corner trace and diag of L (Ld buffer).
// ---------------------------------------------------------------------------
__global__ __launch_bounds__(256) void finalize(const float* __restrict__ W,
                                                const float* __restrict__ Ld,
                                                const int* __restrict__ bsp,
                                                const int* __restrict__ tmaxp,
                                                float* __restrict__ out) {
  __shared__ float rl[4], rq[4];
  int tid = threadIdx.x;
  float lsum = 0.0f;
  for (int d = tid; d < Nn; d += 256) lsum += logf(Ld[d]);
  float qsum = 0.0f;
  if (tid < BSc) qsum = W[tile_off(NBLK - 1, NBLK - 1) + (size_t)tid * NB + tid];
  for (int o = 32; o > 0; o >>= 1) {
    lsum += __shfl_down(lsum, o, 64);
    qsum += __shfl_down(qsum, o, 64);
  }
  int lane = tid & 63, wid = tid >> 6;
  if (lane == 0) { rl[wid] = lsum; rq[wid] = qsum; }
  __syncthreads();
  if (tid == 0) {
    float Lt = rl[0] + rl[1] + rl[2] + rl[3];
    float Qt = rq[0] + rq[1] + rq[2] + rq[3];
    float bsf = (float)bsp[0];
    float tmaxf = (float)tmaxp[0];
    out[0] = -Qt / (2.0f * bsf) + Lt + 0.5f * tmaxf * logf(6.283185307179586f);
  }
}

extern "C" void kernel_launch(void* const* d_in, const int* in_sizes, int n_in,
                              void* d_out, int out_size, void* d_ws, size_t ws_size,
                              hipStream_t stream) {
  const float* Y   = (const float*)d_in[0];
  const float* mu  = (const float*)d_in[1];
  const float* Kp  = (const float*)d_in[2];
  const float* Sg  = (const float*)d_in[3];
  const int*   bsp = (const int*)d_in[4];
  const int*   tmp_= (const int*)d_in[5];
  float* W = (float*)d_ws;                       // 561 tiles fp32: 36.8 MB
  unsigned short* PH = (unsigned short*)(W + (size_t)NTILES * TILE_ELEMS);  // 33 tiles bf16 hi
  unsigned short* PL = PH + (size_t)NBLK * TILE_ELEMS;                      // 33 tiles bf16 lo
  float* Ld = (float*)(PL + (size_t)NBLK * TILE_ELEMS);                     // 4096 diag values
  float* out = (float*)d_out;

  prep<<<NTILES, 256, 0, stream>>>(Y, mu, Kp, Sg, W);

  for (int k = 0; k < NK; ++k) {
    int T = NBLK - (k + 1);
    panel<<<T, 256, 0, stream>>>(W, PH, PL, Ld, k);
    dim3 g(T, T);
    syrk<<<g, 256, 0, stream>>>(PH, PL, W, k);
  }
  finalize<<<1, 256, 0, stream>>>(W, Ld, bsp, tmp_, out);
}